// Round 5
// baseline (43.027 us; speedup 1.0000x reference)
//
#include <hip/hip_runtime.h>

#define S 32768
#define E 256
#define NB 512  // blocks in fused pass; 8 waves x 8 rows each

// K1f: blocks 0..15: q_h (LDS-only, redundant per (h,qt)), kq quarter, c4.
//      blocks 16..79: M2[e][h*256+c] = sum_d Wout[e][h*64+d] * Wv[h*64+d][c]
__global__ void mha_k1f(const float* __restrict__ x, const float* __restrict__ W,
                        const float* __restrict__ inb, const float* __restrict__ Wout,
                        float* __restrict__ kq, float* __restrict__ c4,
                        float* __restrict__ M2) {
  const int t = threadIdx.x;
  if (blockIdx.x < 16) {
    __shared__ __align__(16) float xs[256];
    __shared__ float qls[64];
    __shared__ float red[4][64];
    const int h = blockIdx.x >> 2, qt = blockIdx.x & 3;
    xs[t] = x[t];
    __syncthreads();
    const int lane = t & 63, w = t >> 6;
    const float4 xv = *(const float4*)&xs[lane * 4];
#pragma unroll
    for (int k = 0; k < 16; ++k) {
      const int eloc = w * 16 + k;
      const int row = h * 64 + eloc;
      float4 wv = *(const float4*)&W[(size_t)row * 256 + lane * 4];
      float p = wv.x * xv.x + wv.y * xv.y + wv.z * xv.z + wv.w * xv.w;
#pragma unroll
      for (int m = 1; m < 64; m <<= 1) p += __shfl_xor(p, m);
      if (lane == 0) qls[eloc] = p + inb[row];
    }
    __syncthreads();
    const int cl = t & 63, ds = t >> 6;
    float acc = 0.f;
#pragma unroll
    for (int d2 = 0; d2 < 16; ++d2) {
      const int d = ds * 16 + d2;
      acc += W[(size_t)(256 + h * 64 + d) * 256 + qt * 64 + cl] * qls[d];
    }
    red[ds][cl] = acc;
    __syncthreads();
    if (ds == 0)
      kq[h * 256 + qt * 64 + cl] = red[0][cl] + red[1][cl] + red[2][cl] + red[3][cl];
    if (qt == 0 && t < 64) {
      float v = qls[t] * inb[256 + h * 64 + t];
#pragma unroll
      for (int m = 1; m < 64; m <<= 1) v += __shfl_xor(v, m);
      if (t == 0) c4[h] = v;
    }
  } else {
    __shared__ float wout_t[16][64];
    const int b = blockIdx.x - 16;
    const int h = b >> 4, e0 = (b & 15) * 16;
    for (int i = t; i < 1024; i += 256) {
      const int e = i >> 6, d = i & 63;
      wout_t[e][d] = Wout[(size_t)(e0 + e) * 256 + h * 64 + d];
    }
    __syncthreads();
    const int c = t;
    float acc[16];
#pragma unroll
    for (int e = 0; e < 16; ++e) acc[e] = 0.f;
#pragma unroll 8
    for (int d = 0; d < 64; ++d) {
      const float wv = W[(size_t)(512 + h * 64 + d) * 256 + c];
#pragma unroll
      for (int e = 0; e < 16; ++e) acc[e] += wv * wout_t[e][d];
    }
#pragma unroll
    for (int e = 0; e < 16; ++e)
      M2[(size_t)(e0 + e) * 1024 + h * 256 + c] = acc[e];
  }
}

// K2f: single pass over x, batch-of-8 rows per wave, per-lane head ownership.
// grid NB, block 512 (8 waves x 8 rows).
__global__ void __launch_bounds__(512) mha_k2f(const float* __restrict__ x,
                                               const float* __restrict__ kq,
                                               const float* __restrict__ c4,
                                               float* __restrict__ ypart,
                                               float* __restrict__ mpart,
                                               float* __restrict__ lpart) {
  __shared__ float sml[8][4], sll[8][4];
  __shared__ __align__(16) float yls[8][1024];
  const int t = threadIdx.x;
  const int lane = t & 63, w = t >> 6;
  const int hme = lane & 3;
  const float4 kq0 = *(const float4*)&kq[0 * 256 + lane * 4];
  const float4 kq1 = *(const float4*)&kq[1 * 256 + lane * 4];
  const float4 kq2 = *(const float4*)&kq[2 * 256 + lane * 4];
  const float4 kq3 = *(const float4*)&kq[3 * 256 + lane * 4];
  const float c4v = c4[hme];

  // issue all 8 row loads up front (8 outstanding per wave)
  const int r0 = (blockIdx.x * 8 + w) * 8;
  float4 xv[8];
#pragma unroll
  for (int r = 0; r < 8; ++r)
    xv[r] = *(const float4*)&x[(size_t)(r0 + r) * 256 + lane * 4];

  // 8 independent butterfly chains -> v[r] = score of head (lane&3) for row r0+r
  float v[8];
#pragma unroll
  for (int r = 0; r < 8; ++r) {
    float p0 = xv[r].x * kq0.x + xv[r].y * kq0.y + xv[r].z * kq0.z + xv[r].w * kq0.w;
    float p1 = xv[r].x * kq1.x + xv[r].y * kq1.y + xv[r].z * kq1.z + xv[r].w * kq1.w;
    float p2 = xv[r].x * kq2.x + xv[r].y * kq2.y + xv[r].z * kq2.z + xv[r].w * kq2.w;
    float p3 = xv[r].x * kq3.x + xv[r].y * kq3.y + xv[r].z * kq3.z + xv[r].w * kq3.w;
    const bool b1 = (lane & 2) != 0;
    float keep0 = b1 ? p2 : p0, send0 = b1 ? p0 : p2;
    keep0 += __shfl_xor(send0, 2);
    float keep1 = b1 ? p3 : p1, send1 = b1 ? p1 : p3;
    keep1 += __shfl_xor(send1, 2);
    const bool b0 = (lane & 1) != 0;
    float vv = b0 ? keep1 : keep0, sv = b0 ? keep0 : keep1;
    vv += __shfl_xor(sv, 1);
    vv += __shfl_xor(vv, 4);
    vv += __shfl_xor(vv, 8);
    vv += __shfl_xor(vv, 16);
    vv += __shfl_xor(vv, 32);
    v[r] = (vv + c4v) * 0.125f;
  }

  // wave-level max for own head (this wave's whole assignment -> no online state)
  float m = v[0];
#pragma unroll
  for (int r = 1; r < 8; ++r) m = fmaxf(m, v[r]);

  // e + rotated accumulation: a[k] accumulates head (lane&3)^k
  float l = 0.f;
  float4 a[4];
#pragma unroll
  for (int k = 0; k < 4; ++k) a[k] = (float4){0.f, 0.f, 0.f, 0.f};
#pragma unroll
  for (int r = 0; r < 8; ++r) {
    const float e0 = __expf(v[r] - m);
    l += e0;
    const float e1 = __shfl_xor(e0, 1);
    const float e2 = __shfl_xor(e0, 2);
    const float e3 = __shfl_xor(e0, 3);
    a[0].x += e0 * xv[r].x; a[0].y += e0 * xv[r].y; a[0].z += e0 * xv[r].z; a[0].w += e0 * xv[r].w;
    a[1].x += e1 * xv[r].x; a[1].y += e1 * xv[r].y; a[1].z += e1 * xv[r].z; a[1].w += e1 * xv[r].w;
    a[2].x += e2 * xv[r].x; a[2].y += e2 * xv[r].y; a[2].z += e2 * xv[r].z; a[2].w += e2 * xv[r].w;
    a[3].x += e3 * xv[r].x; a[3].y += e3 * xv[r].y; a[3].z += e3 * xv[r].z; a[3].w += e3 * xv[r].w;
  }

  if (lane < 4) { sml[w][lane] = m; sll[w][lane] = l; }
  __syncthreads();

  // block max per head (broadcast LDS reads), rescale own-wave partials, store
#pragma unroll
  for (int k = 0; k < 4; ++k) {
    const int h = hme ^ k;
    float mb = sml[0][h];
#pragma unroll
    for (int i = 1; i < 8; ++i) mb = fmaxf(mb, sml[i][h]);
    const float f = __expf(sml[w][h] - mb);
    float4 av;
    av.x = a[k].x * f; av.y = a[k].y * f; av.z = a[k].z * f; av.w = a[k].w * f;
    *(float4*)&yls[w][h * 256 + lane * 4] = av;
  }
  __syncthreads();

  if (t < 4) {
    float mb = sml[0][t];
#pragma unroll
    for (int i = 1; i < 8; ++i) mb = fmaxf(mb, sml[i][t]);
    float lb = 0.f;
#pragma unroll
    for (int i = 0; i < 8; ++i) lb += sll[i][t] * __expf(sml[i][t] - mb);
    mpart[t * NB + blockIdx.x] = mb;
    lpart[t * NB + blockIdx.x] = lb;
  }
  float* yp = &ypart[(size_t)blockIdx.x * 1024];
  for (int o = t; o < 1024; o += 512) {
    float s = yls[0][o] + yls[1][o] + yls[2][o] + yls[3][o] +
              yls[4][o] + yls[5][o] + yls[6][o] + yls[7][o];
    yp[o] = s;
  }
}

// K3r: global rescale-reduce -> yv (scaled by 1/l per head).
// grid 64 (16 outputs each), block 256 (16 b-groups x 16 outputs).
__global__ void mha_k3r(const float* __restrict__ ypart, const float* __restrict__ mpart,
                        const float* __restrict__ lpart, float* __restrict__ yv) {
  __shared__ float mred[256];
  __shared__ float lredl[256];
  __shared__ float scales[NB];
  __shared__ float sred[16][16];
  __shared__ float mg_s, linv_s;
  const int t = threadIdx.x;
  const int h = blockIdx.x >> 4;
  const int o0 = blockIdx.x * 16;
  float mm = fmaxf(mpart[h * NB + t], mpart[h * NB + t + 256]);
  mred[t] = mm;
  __syncthreads();
  for (int s = 128; s > 0; s >>= 1) {
    if (t < s) mred[t] = fmaxf(mred[t], mred[t + s]);
    __syncthreads();
  }
  if (t == 0) mg_s = mred[0];
  __syncthreads();
  const float mg = mg_s;
  float lp = 0.f;
#pragma unroll
  for (int i = t; i < NB; i += 256) {
    float sc = __expf(mpart[h * NB + i] - mg);
    scales[i] = sc;
    lp += lpart[h * NB + i] * sc;
  }
  lredl[t] = lp;
  __syncthreads();
  for (int s = 128; s > 0; s >>= 1) {
    if (t < s) lredl[t] += lredl[t + s];
    __syncthreads();
  }
  if (t == 0) linv_s = 1.0f / lredl[0];
  __syncthreads();
  const float inv = linv_s;
  const int ol = t & 15, bg = t >> 4;
  const int o = o0 + ol;
  float s = 0.f;
#pragma unroll 8
  for (int j = 0; j < 32; ++j) {
    const int b = bg * 32 + j;
    s += ypart[(size_t)b * 1024 + o] * scales[b];
  }
  sred[bg][ol] = s;
  __syncthreads();
  if (t < 16) {
    float tot = 0.f;
#pragma unroll
    for (int g = 0; g < 16; ++g) tot += sred[g][t];
    yv[o0 + t] = tot * inv;
  }
}

// K4o: out[e] = M2flat[e].yv + Wout[e].bv + bout[e]. grid 16 (16 outputs each), block 256.
__global__ void mha_k4o(const float* __restrict__ M2, const float* __restrict__ yv,
                        const float* __restrict__ Wout, const float* __restrict__ inb,
                        const float* __restrict__ bout, float* __restrict__ out) {
  __shared__ __align__(16) float yls[1024];
  __shared__ __align__(16) float bvls[256];
  __shared__ float smo[256];
  const int t = threadIdx.x;
  for (int i = t; i < 1024; i += 256) yls[i] = yv[i];
  if (t < 256) bvls[t] = inb[512 + t];
  __syncthreads();
  const int og = t >> 4, seg = t & 15;
  const int e = blockIdx.x * 16 + og;
  float acc = 0.f;
  const float4* m4 = (const float4*)&M2[(size_t)e * 1024 + seg * 64];
  const float4* y4 = (const float4*)&yls[seg * 64];
#pragma unroll
  for (int j = 0; j < 16; ++j) {
    float4 mv = m4[j];
    float4 yy = y4[j];
    acc += mv.x * yy.x + mv.y * yy.y + mv.z * yy.z + mv.w * yy.w;
  }
  if (seg < 4) {
    const float4* w4 = (const float4*)&Wout[(size_t)e * 256 + seg * 64];
    const float4* b4 = (const float4*)&bvls[seg * 64];
#pragma unroll
    for (int j = 0; j < 16; ++j) {
      float4 wv = w4[j];
      float4 bb = b4[j];
      acc += wv.x * bb.x + wv.y * bb.y + wv.z * bb.z + wv.w * bb.w;
    }
  }
  smo[t] = acc;
  __syncthreads();
  if (t < 16) {
    float s = bout[blockIdx.x * 16 + t];
#pragma unroll
    for (int i = 0; i < 16; ++i) s += smo[t * 16 + i];
    out[blockIdx.x * 16 + t] = s;
  }
}

extern "C" void kernel_launch(void* const* d_in, const int* in_sizes, int n_in,
                              void* d_out, int out_size, void* d_ws, size_t ws_size,
                              hipStream_t stream) {
  const float* x = (const float*)d_in[0];
  const float* W = (const float*)d_in[1];      // in_proj_weight (768x256)
  const float* inb = (const float*)d_in[2];    // in_proj_bias (768)
  const float* Wout = (const float*)d_in[3];   // out_proj_weight (256x256)
  const float* bout = (const float*)d_in[4];   // out_proj_bias (256)
  float* out = (float*)d_out;
  float* ws = (float*)d_ws;

  float* c4 = ws;                                // 4 (+pad to 64)
  float* kq = ws + 64;                           // 1024
  float* mpart = ws + 1088;                      // 2048
  float* lpart = ws + 3136;                      // 2048
  float* yv = ws + 5184;                         // 1024
  float* M2 = ws + 6208;                         // 256*1024 = 262144
  float* ypart = ws + 268352;                    // NB*1024 = 524288

  mha_k1f<<<80, 256, 0, stream>>>(x, W, inb, Wout, kq, c4, M2);
  mha_k2f<<<NB, 512, 0, stream>>>(x, kq, c4, ypart, mpart, lpart);
  mha_k3r<<<64, 256, 0, stream>>>(ypart, mpart, lpart, yv);
  mha_k4o<<<16, 256, 0, stream>>>(M2, yv, Wout, inb, bout, out);
}

// Round 8
// 32.077 us; speedup vs baseline: 1.3414x; 1.3414x over previous
//
#include <hip/hip_runtime.h>
#include <hip/hip_cooperative_groups.h>
namespace cg = cooperative_groups;

#define S 32768
#define NBLK 256  // fused-pass blocks; 8 waves x 16 rows each

// ws layout (floats): c4 @0 (pad 64) | kq @64 | mpart @1088 | lpart @2112 |
//                     yv @3136 | M2 @4160 (262144) | ypart @266304 (262144)

__device__ __forceinline__ float dot4(float4 a, float4 b) {
  return a.x * b.x + a.y * b.y + a.z * b.z + a.w * b.w;
}

// ---------------- Phase A: kq/c4 (blocks 0..15), M2 (blocks 16..143) ----------------
__device__ __forceinline__ void phaseA(const float* __restrict__ x, const float* __restrict__ W,
                                       const float* __restrict__ inb, const float* __restrict__ Wout,
                                       float* __restrict__ kq, float* __restrict__ c4,
                                       float* __restrict__ M2, float* sh, int bid, int t) {
  const int lane = t & 63, w = t >> 6;
  if (bid < 16) {
    float* xs = sh;          // 256
    float* qls = sh + 256;   // 64
    float* red = sh + 320;   // 512
    const int h = bid >> 2, qt = bid & 3;
    if (t < 256) xs[t] = x[t];
    __syncthreads();
    const float4 xv = *(const float4*)&xs[lane * 4];
#pragma unroll
    for (int k = 0; k < 8; ++k) {
      const int eloc = w * 8 + k;
      const int row = h * 64 + eloc;
      float4 wv = *(const float4*)&W[(size_t)row * 256 + lane * 4];
      float p = dot4(wv, xv);
#pragma unroll
      for (int m = 1; m < 64; m <<= 1) p += __shfl_xor(p, m);
      if (lane == 0) qls[eloc] = p + inb[row];
    }
    __syncthreads();
    const int cl = t & 63, ds = t >> 6;
    float acc = 0.f;
#pragma unroll
    for (int d2 = 0; d2 < 8; ++d2) {
      const int d = ds * 8 + d2;
      acc += W[(size_t)(256 + h * 64 + d) * 256 + qt * 64 + cl] * qls[d];
    }
    red[ds * 64 + cl] = acc;
    __syncthreads();
    if (ds == 0) {
      float s = 0.f;
#pragma unroll
      for (int i = 0; i < 8; ++i) s += red[i * 64 + cl];
      kq[h * 256 + qt * 64 + cl] = s;
    }
    if (qt == 0 && t < 64) {
      float v = qls[t] * inb[256 + h * 64 + t];
#pragma unroll
      for (int m = 1; m < 64; m <<= 1) v += __shfl_xor(v, m);
      if (t == 0) c4[h] = v;
    }
  } else if (bid < 144) {
    float* wout_t = sh;  // [8][64]
    const int b2 = bid - 16;
    const int tile = b2 >> 1, sub = b2 & 1;
    const int h = tile >> 4, e0 = (tile & 15) * 16 + sub * 8;
    {
      const int e = t >> 6, d = t & 63;
      wout_t[e * 64 + d] = Wout[(size_t)(e0 + e) * 256 + h * 64 + d];
    }
    __syncthreads();
    const int c = t & 255, eh = t >> 8;
    float acc[4] = {0.f, 0.f, 0.f, 0.f};
#pragma unroll 8
    for (int d = 0; d < 64; ++d) {
      const float wv = W[(size_t)(512 + h * 64 + d) * 256 + c];
#pragma unroll
      for (int e = 0; e < 4; ++e) acc[e] += wv * wout_t[(eh * 4 + e) * 64 + d];
    }
#pragma unroll
    for (int e = 0; e < 4; ++e)
      M2[(size_t)(e0 + eh * 4 + e) * 1024 + h * 256 + c] = acc[e];
  }
}

// ---------------- Phase B: fused scores + softmax partials ----------------
__device__ __forceinline__ float bscore(float4 xv, float4 kq0, float4 kq1, float4 kq2,
                                        float4 kq3, float c4v, int lane) {
  float p0 = dot4(xv, kq0), p1 = dot4(xv, kq1), p2 = dot4(xv, kq2), p3 = dot4(xv, kq3);
  const bool b1 = (lane & 2) != 0;
  float keep0 = b1 ? p2 : p0, send0 = b1 ? p0 : p2;
  keep0 += __shfl_xor(send0, 2);
  float keep1 = b1 ? p3 : p1, send1 = b1 ? p1 : p3;
  keep1 += __shfl_xor(send1, 2);
  const bool b0 = (lane & 1) != 0;
  float vv = b0 ? keep1 : keep0, sv = b0 ? keep0 : keep1;
  vv += __shfl_xor(sv, 1);
  vv += __shfl_xor(vv, 4);
  vv += __shfl_xor(vv, 8);
  vv += __shfl_xor(vv, 16);
  vv += __shfl_xor(vv, 32);
  return (vv + c4v) * 0.125f;
}

__device__ __forceinline__ void phaseB(const float* __restrict__ x, const float* __restrict__ kq,
                                       const float* __restrict__ c4, float* __restrict__ ypart,
                                       float* __restrict__ mpart, float* __restrict__ lpart,
                                       float* sh, int bid, int t) {
  float* yls = sh;          // 8192
  float* sml = sh + 8192;   // 32
  float* sll = sh + 8224;   // 32
  const int lane = t & 63, w = t >> 6;
  const int hme = lane & 3;
  const float4 kq0 = *(const float4*)&kq[0 * 256 + lane * 4];
  const float4 kq1 = *(const float4*)&kq[1 * 256 + lane * 4];
  const float4 kq2 = *(const float4*)&kq[2 * 256 + lane * 4];
  const float4 kq3 = *(const float4*)&kq[3 * 256 + lane * 4];
  const float c4v = c4[hme];

  const int r0 = bid * 128 + w * 16;
  float4 xvA[8], xvB[8];
#pragma unroll
  for (int r = 0; r < 8; ++r)
    xvA[r] = *(const float4*)&x[(size_t)(r0 + r) * 256 + lane * 4];
#pragma unroll
  for (int r = 0; r < 8; ++r)
    xvB[r] = *(const float4*)&x[(size_t)(r0 + 8 + r) * 256 + lane * 4];

  float vA[8];
#pragma unroll
  for (int r = 0; r < 8; ++r) vA[r] = bscore(xvA[r], kq0, kq1, kq2, kq3, c4v, lane);
  float m = vA[0];
#pragma unroll
  for (int r = 1; r < 8; ++r) m = fmaxf(m, vA[r]);

  float l = 0.f;
  float4 a[4];
#pragma unroll
  for (int k = 0; k < 4; ++k) a[k] = (float4){0.f, 0.f, 0.f, 0.f};
#pragma unroll
  for (int r = 0; r < 8; ++r) {
    const float e0 = __expf(vA[r] - m);
    l += e0;
    const float e1 = __shfl_xor(e0, 1);
    const float e2 = __shfl_xor(e0, 2);
    const float e3 = __shfl_xor(e0, 3);
    a[0].x += e0 * xvA[r].x; a[0].y += e0 * xvA[r].y; a[0].z += e0 * xvA[r].z; a[0].w += e0 * xvA[r].w;
    a[1].x += e1 * xvA[r].x; a[1].y += e1 * xvA[r].y; a[1].z += e1 * xvA[r].z; a[1].w += e1 * xvA[r].w;
    a[2].x += e2 * xvA[r].x; a[2].y += e2 * xvA[r].y; a[2].z += e2 * xvA[r].z; a[2].w += e2 * xvA[r].w;
    a[3].x += e3 * xvA[r].x; a[3].y += e3 * xvA[r].y; a[3].z += e3 * xvA[r].z; a[3].w += e3 * xvA[r].w;
  }

  float vB[8];
#pragma unroll
  for (int r = 0; r < 8; ++r) vB[r] = bscore(xvB[r], kq0, kq1, kq2, kq3, c4v, lane);
  float mB = vB[0];
#pragma unroll
  for (int r = 1; r < 8; ++r) mB = fmaxf(mB, vB[r]);

  // ---- FIXED online merge: per-head rescale factors via lane shuffles ----
  // m, mB, l are own-head (lane&3) values, but a[k] holds head (lane&3)^k and
  // must be rescaled by THAT head's factor.
  {
    const float mN = fmaxf(m, mB);
    const float fown = __expf(m - mN);  // own-head rescale (1.0 if no update)
    l *= fown;
    const float f1 = __shfl_xor(fown, 1);
    const float f2 = __shfl_xor(fown, 2);
    const float f3 = __shfl_xor(fown, 3);
    a[0].x *= fown; a[0].y *= fown; a[0].z *= fown; a[0].w *= fown;
    a[1].x *= f1;   a[1].y *= f1;   a[1].z *= f1;   a[1].w *= f1;
    a[2].x *= f2;   a[2].y *= f2;   a[2].z *= f2;   a[2].w *= f2;
    a[3].x *= f3;   a[3].y *= f3;   a[3].z *= f3;   a[3].w *= f3;
    m = mN;
  }
#pragma unroll
  for (int r = 0; r < 8; ++r) {
    const float e0 = __expf(vB[r] - m);
    l += e0;
    const float e1 = __shfl_xor(e0, 1);
    const float e2 = __shfl_xor(e0, 2);
    const float e3 = __shfl_xor(e0, 3);
    a[0].x += e0 * xvB[r].x; a[0].y += e0 * xvB[r].y; a[0].z += e0 * xvB[r].z; a[0].w += e0 * xvB[r].w;
    a[1].x += e1 * xvB[r].x; a[1].y += e1 * xvB[r].y; a[1].z += e1 * xvB[r].z; a[1].w += e1 * xvB[r].w;
    a[2].x += e2 * xvB[r].x; a[2].y += e2 * xvB[r].y; a[2].z += e2 * xvB[r].z; a[2].w += e2 * xvB[r].w;
    a[3].x += e3 * xvB[r].x; a[3].y += e3 * xvB[r].y; a[3].z += e3 * xvB[r].z; a[3].w += e3 * xvB[r].w;
  }

  __syncthreads();  // sh reuse safety (fresh in fallback, post-grid-sync in coop)
  if (lane < 4) { sml[w * 4 + lane] = m; sll[w * 4 + lane] = l; }
  __syncthreads();

#pragma unroll
  for (int k = 0; k < 4; ++k) {
    const int h = hme ^ k;
    float mb = sml[h];
#pragma unroll
    for (int i = 1; i < 8; ++i) mb = fmaxf(mb, sml[i * 4 + h]);
    const float f = __expf(sml[w * 4 + h] - mb);
    float4 av;
    av.x = a[k].x * f; av.y = a[k].y * f; av.z = a[k].z * f; av.w = a[k].w * f;
    *(float4*)&yls[w * 1024 + h * 256 + lane * 4] = av;
  }
  __syncthreads();

  if (t < 4) {
    float mb = sml[t];
#pragma unroll
    for (int i = 1; i < 8; ++i) mb = fmaxf(mb, sml[i * 4 + t]);
    float lb = 0.f;
#pragma unroll
    for (int i = 0; i < 8; ++i) lb += sll[i * 4 + t] * __expf(sml[i * 4 + t] - mb);
    mpart[t * NBLK + bid] = mb;
    lpart[t * NBLK + bid] = lb;
  }
  float* yp = &ypart[(size_t)bid * 1024];
#pragma unroll
  for (int o = t; o < 1024; o += 512) {
    float s = 0.f;
#pragma unroll
    for (int i = 0; i < 8; ++i) s += yls[i * 1024 + o];
    yp[o] = s;
  }
}

// ---------------- Phase C: rescale-reduce -> yv (blocks 0..63) ----------------
__device__ __forceinline__ void phaseC(const float* __restrict__ ypart, const float* __restrict__ mpart,
                                       const float* __restrict__ lpart, float* __restrict__ yv,
                                       float* sh, int bid, int t) {
  float* mred = sh;           // 256
  float* scales = sh + 256;   // 256
  float* lred = sh + 512;     // 256
  float* sred = sh + 768;     // 512
  const int h = bid >> 4;
  const int o0 = bid * 16;
  if (t < 256) mred[t] = mpart[h * 256 + t];
  __syncthreads();
  for (int s = 128; s > 0; s >>= 1) {
    if (t < s) mred[t] = fmaxf(mred[t], mred[t + s]);
    __syncthreads();
  }
  const float mg = mred[0];
  if (t < 256) {
    const float sc = __expf(mpart[h * 256 + t] - mg);
    scales[t] = sc;
    lred[t] = lpart[h * 256 + t] * sc;
  }
  __syncthreads();
  for (int s = 128; s > 0; s >>= 1) {
    if (t < s) lred[t] += lred[t + s];
    __syncthreads();
  }
  const float inv = 1.0f / lred[0];
  const int ol = t & 15, bg = t >> 4;  // 32 groups x 8 partial-rows each
  float s = 0.f;
#pragma unroll
  for (int j = 0; j < 8; ++j) {
    const int b = bg * 8 + j;
    s += ypart[(size_t)b * 1024 + o0 + ol] * scales[b];
  }
  sred[bg * 16 + ol] = s;
  __syncthreads();
  if (t < 16) {
    float tot = 0.f;
#pragma unroll
    for (int g = 0; g < 32; ++g) tot += sred[g * 16 + t];
    yv[o0 + t] = tot * inv;
  }
}

// ---------------- Phase D: out = M2.yv + Wout.bv + bout (blocks 0..15) ----------------
__device__ __forceinline__ void phaseD(const float* __restrict__ M2, const float* __restrict__ yv,
                                       const float* __restrict__ Wout, const float* __restrict__ inb,
                                       const float* __restrict__ bout, float* __restrict__ out,
                                       float* sh, int bid, int t) {
  float* yls = sh;          // 1024
  float* bvls = sh + 1024;  // 256
  float* smo = sh + 1280;   // 512
  for (int i = t; i < 1024; i += 512) yls[i] = yv[i];
  if (t < 256) bvls[t] = inb[512 + t];
  __syncthreads();
  const int og = t >> 5, seg = t & 31;
  const int e = bid * 16 + og;
  float acc = 0.f;
  const float4* m4 = (const float4*)&M2[(size_t)e * 1024 + seg * 32];
  const float4* y4 = (const float4*)&yls[seg * 32];
#pragma unroll
  for (int j = 0; j < 8; ++j) acc += dot4(m4[j], y4[j]);
  if (seg < 8) {
    const float4* w4 = (const float4*)&Wout[(size_t)e * 256 + seg * 32];
    const float4* b4 = (const float4*)&bvls[seg * 32];
#pragma unroll
    for (int j = 0; j < 8; ++j) acc += dot4(w4[j], b4[j]);
  }
  smo[og * 32 + seg] = acc;
  __syncthreads();
  if (t < 16) {
    float s = bout[bid * 16 + t];
#pragma unroll
    for (int i = 0; i < 32; ++i) s += smo[t * 32 + i];
    out[bid * 16 + t] = s;
  }
}

// ---------------- Cooperative all-in-one ----------------
__global__ void __launch_bounds__(512, 2) mha_coop(const float* __restrict__ x,
                                                   const float* __restrict__ W,
                                                   const float* __restrict__ inb,
                                                   const float* __restrict__ Wout,
                                                   const float* __restrict__ bout,
                                                   float* __restrict__ out,
                                                   float* __restrict__ ws) {
  __shared__ __align__(16) float sh[8448];
  float* c4 = ws;
  float* kq = ws + 64;
  float* mpart = ws + 1088;
  float* lpart = ws + 2112;
  float* yv = ws + 3136;
  float* M2 = ws + 4160;
  float* ypart = ws + 266304;
  const int t = threadIdx.x, bid = blockIdx.x;
  cg::grid_group grid = cg::this_grid();
  phaseA(x, W, inb, Wout, kq, c4, M2, sh, bid, t);
  grid.sync();
  phaseB(x, kq, c4, ypart, mpart, lpart, sh, bid, t);
  grid.sync();
  if (bid < 64) phaseC(ypart, mpart, lpart, yv, sh, bid, t);
  grid.sync();
  if (bid < 16) phaseD(M2, yv, Wout, inb, bout, out, sh, bid, t);
}

// ---------------- Fallback chain (same phases, 4 launches) ----------------
__global__ void __launch_bounds__(512) fb_A(const float* __restrict__ x, const float* __restrict__ W,
                                            const float* __restrict__ inb, const float* __restrict__ Wout,
                                            float* __restrict__ ws) {
  __shared__ __align__(16) float sh[832];
  phaseA(x, W, inb, Wout, ws + 64, ws, ws + 4160, sh, blockIdx.x, threadIdx.x);
}
__global__ void __launch_bounds__(512) fb_B(const float* __restrict__ x, float* __restrict__ ws) {
  __shared__ __align__(16) float sh[8256];
  phaseB(x, ws + 64, ws, ws + 266304, ws + 1088, ws + 2112, sh, blockIdx.x, threadIdx.x);
}
__global__ void __launch_bounds__(512) fb_C(float* __restrict__ ws) {
  __shared__ __align__(16) float sh[1280];
  phaseC(ws + 266304, ws + 1088, ws + 2112, ws + 3136, sh, blockIdx.x, threadIdx.x);
}
__global__ void __launch_bounds__(512) fb_D(const float* __restrict__ Wout, const float* __restrict__ inb,
                                            const float* __restrict__ bout, float* __restrict__ out,
                                            float* __restrict__ ws) {
  __shared__ __align__(16) float sh[1792];
  phaseD(ws + 4160, ws + 3136, Wout, inb, bout, out, sh, blockIdx.x, threadIdx.x);
}

extern "C" void kernel_launch(void* const* d_in, const int* in_sizes, int n_in,
                              void* d_out, int out_size, void* d_ws, size_t ws_size,
                              hipStream_t stream) {
  const float* x = (const float*)d_in[0];
  const float* W = (const float*)d_in[1];
  const float* inb = (const float*)d_in[2];
  const float* Wout = (const float*)d_in[3];
  const float* bout = (const float*)d_in[4];
  float* out = (float*)d_out;
  float* ws = (float*)d_ws;

  // Host-side coop feasibility precheck (device queries only; graph-capture safe,
  // deterministic across calls on a fixed device).
  int dev = 0;
  (void)hipGetDevice(&dev);
  int coopAttr = 0, ncu = 0, occ = 0;
  bool coop = (hipDeviceGetAttribute(&coopAttr, hipDeviceAttributeCooperativeLaunch, dev) == hipSuccess) &&
              coopAttr != 0;
  coop = coop &&
         (hipDeviceGetAttribute(&ncu, hipDeviceAttributeMultiprocessorCount, dev) == hipSuccess);
  coop = coop &&
         (hipOccupancyMaxActiveBlocksPerMultiprocessor(&occ, mha_coop, 512, 0) == hipSuccess);
  coop = coop && (occ * ncu >= NBLK);

  if (coop) {
    void* args[] = {(void*)&x, (void*)&W, (void*)&inb, (void*)&Wout,
                    (void*)&bout, (void*)&out, (void*)&ws};
    if (hipLaunchCooperativeKernel((const void*)mha_coop, dim3(NBLK), dim3(512),
                                   args, 0, stream) == hipSuccess)
      return;
  }
  fb_A<<<144, 512, 0, stream>>>(x, W, inb, Wout, ws);
  fb_B<<<NBLK, 512, 0, stream>>>(x, ws);
  fb_C<<<64, 512, 0, stream>>>(ws);
  fb_D<<<16, 512, 0, stream>>>(Wout, inb, bout, out, ws);
}